// Round 10
// baseline (2683.838 us; speedup 1.0000x reference)
//
#include <hip/hip_runtime.h>

typedef float v2f __attribute__((ext_vector_type(2)));
typedef float v4f __attribute__((ext_vector_type(4)));

// Tsit5 coefficients (b7 = 0 -> 6 stages)
__device__ constexpr float cA21 = 0.161f;
__device__ constexpr float cA31 = -0.008480655492356989f, cA32 = 0.335480655492357f;
__device__ constexpr float cA41 = 2.8971530571054935f,  cA42 = -6.359448489975075f,  cA43 = 4.3622954328695815f;
__device__ constexpr float cA51 = 5.325864828439257f,   cA52 = -11.748883564062828f, cA53 = 7.4955393428898365f, cA54 = -0.09249506636175525f;
__device__ constexpr float cA61 = 5.86145544294642f,    cA62 = -12.92096931784711f,  cA63 = 8.159367898576159f,  cA64 = -0.071584973281401f, cA65 = -0.028269050394068383f;
__device__ constexpr float cB1 = 0.09646076681806523f,  cB2 = 0.01f,                 cB3 = 0.4798896504144996f;
__device__ constexpr float cB4 = 1.379008574103742f,    cB5 = -3.290069515436081f,   cB6 = 2.324710524099774f;

#define N_D 16
#define N_H 32
#define N_T 40
#define N_B 8192

// Intra-wave producer->consumer fence (single-wave exchange, no s_barrier needed).
__device__ __forceinline__ void wave_fence() {
    asm volatile("s_waitcnt lgkmcnt(0)" ::: "memory");
}

#define PIN2(v)  asm volatile("" : "+v"(v))

// Packed fp32 FMA (CDNA2+ v_pk_fma_f32), weight broadcast via op_sel word select:
//  LO: d.{lo,hi} += a.{lo,hi} * w.word0   (weight = w.x for both trajectories)
//  HI: d.{lo,hi} += a.{lo,hi} * w.word1   (weight = w.y)
#define PKFMA_LO(d,a,w) asm("v_pk_fma_f32 %0, %1, %2, %0 op_sel:[0,0,0] op_sel_hi:[1,0,1]" : "+v"(d) : "v"(a), "v"(w))
#define PKFMA_HI(d,a,w) asm("v_pk_fma_f32 %0, %1, %2, %0 op_sel:[0,1,0] op_sel_hi:[1,1,1]" : "+v"(d) : "v"(a), "v"(w))

__device__ __forceinline__ float softplus_f(float x) {
    float e = __expf(-fabsf(x));
    return fmaxf(x, 0.0f) + __logf(1.0f + e);
}

__device__ __forceinline__ v2f vadd2(v2f a, v2f b) { return a + b; }
__device__ __forceinline__ v2f vmulc(float c, v2f a) { return (v2f){c * a.x, c * a.y}; }
__device__ __forceinline__ v2f vfmac(float c, v2f a, v2f b) {
    return (v2f){fmaf(c, a.x, b.x), fmaf(c, a.y, b.y)};
}
__device__ __forceinline__ v2f shxor(v2f v, int m) {
    v2f r; r.x = __shfl_xor(v.x, m, 64); r.y = __shfl_xor(v.y, m, 64); return r;
}
__device__ __forceinline__ v2f lo2(v4f u) { return __builtin_shufflevector(u, u, 0, 1); }
__device__ __forceinline__ v2f hi2(v4f u) { return __builtin_shufflevector(u, u, 2, 3); }

// Wave = 64 lanes = 2 trajectories (packed in v2f pairs) x 32 neurons.
// Activations live in LDS as {traj0,traj1} pairs; each v_pk_fma_f32 does both
// trajectories at once (96 -> 48 MAC instrs/eval/lane). Each lane keeps its
// row-HALF of each weight column as float2 row-pairs (48 VGPRs), applied to
// both pair halves via op_sel word-broadcast. One shfl_xor(32) pair-exchange
// completes the dots; no cndmask select chains.
__global__ void __launch_bounds__(256)
__attribute__((amdgpu_waves_per_eu(4, 4)))
ode_tsit5_kernel(
    const float* __restrict__ x0s, const float* __restrict__ t_eval,
    const float* __restrict__ W0, const float* __restrict__ b0,
    const float* __restrict__ W1, const float* __restrict__ b1,
    const float* __restrict__ W2, const float* __restrict__ b2,
    const float* __restrict__ W3, const float* __restrict__ b3,
    float* __restrict__ out)
{
    __shared__ alignas(16) v2f ybufP[4][N_D];
    __shared__ alignas(16) v2f AbufP[4][N_H];
    __shared__ alignas(16) v2f BbufP[4][N_H];

    const int tid  = threadIdx.x;
    const int wid  = tid >> 6;
    const int lane = tid & 63;
    const int t    = lane >> 5;   // row-half owned (and which pair-word this lane extracts)
    const int j    = lane & 31;   // neuron / column index
    const int o    = j & 15;      // state dim (layers 0 and 3)
    const int h    = j >> 4;      // 16-row half of W3 covered
    const int traj0 = (blockIdx.x * 4 + wid) * 2;
    const int traj1 = traj0 + 1;
    const bool lane16 = (lane < 16);   // t==0 && h==0 writers

    v2f* ybP = ybufP[wid];
    v2f* AbP = AbufP[wid];
    v2f* BbP = BbufP[wid];

    // Weight row-pairs: w*_q = {W[row 2q], W[row 2q+1]} of this lane's column.
    v2f w0_0, w0_1, w0_2, w0_3;
    v2f w1_0, w1_1, w1_2, w1_3, w1_4, w1_5, w1_6, w1_7;
    v2f w2_0, w2_1, w2_2, w2_3, w2_4, w2_5, w2_6, w2_7;
    v2f w3_0, w3_1, w3_2, w3_3;
#define LDW(dst, Wp, r0, col, LD) dst = (v2f){Wp[(r0) * LD + (col)], Wp[((r0) + 1) * LD + (col)]}
    LDW(w0_0, W0, t * 8 + 0, j, N_H); LDW(w0_1, W0, t * 8 + 2, j, N_H);
    LDW(w0_2, W0, t * 8 + 4, j, N_H); LDW(w0_3, W0, t * 8 + 6, j, N_H);
    LDW(w1_0, W1, t * 16 + 0,  j, N_H); LDW(w1_1, W1, t * 16 + 2,  j, N_H);
    LDW(w1_2, W1, t * 16 + 4,  j, N_H); LDW(w1_3, W1, t * 16 + 6,  j, N_H);
    LDW(w1_4, W1, t * 16 + 8,  j, N_H); LDW(w1_5, W1, t * 16 + 10, j, N_H);
    LDW(w1_6, W1, t * 16 + 12, j, N_H); LDW(w1_7, W1, t * 16 + 14, j, N_H);
    LDW(w2_0, W2, t * 16 + 0,  j, N_H); LDW(w2_1, W2, t * 16 + 2,  j, N_H);
    LDW(w2_2, W2, t * 16 + 4,  j, N_H); LDW(w2_3, W2, t * 16 + 6,  j, N_H);
    LDW(w2_4, W2, t * 16 + 8,  j, N_H); LDW(w2_5, W2, t * 16 + 10, j, N_H);
    LDW(w2_6, W2, t * 16 + 12, j, N_H); LDW(w2_7, W2, t * 16 + 14, j, N_H);
    LDW(w3_0, W3, h * 16 + t * 8 + 0, o, N_D); LDW(w3_1, W3, h * 16 + t * 8 + 2, o, N_D);
    LDW(w3_2, W3, h * 16 + t * 8 + 4, o, N_D); LDW(w3_3, W3, h * 16 + t * 8 + 6, o, N_D);
#undef LDW
    v2f b0p = (v2f){b0[j], b0[j]};
    v2f b1p = (v2f){b1[j], b1[j]};
    v2f b2p = (v2f){b2[j], b2[j]};
    v2f b3p = (v2f){b3[o], b3[o]};

    PIN2(w0_0); PIN2(w0_1); PIN2(w0_2); PIN2(w0_3);
    PIN2(w1_0); PIN2(w1_1); PIN2(w1_2); PIN2(w1_3);
    PIN2(w1_4); PIN2(w1_5); PIN2(w1_6); PIN2(w1_7);
    PIN2(w2_0); PIN2(w2_1); PIN2(w2_2); PIN2(w2_3);
    PIN2(w2_4); PIN2(w2_5); PIN2(w2_6); PIN2(w2_7);
    PIN2(w3_0); PIN2(w3_1); PIN2(w3_2); PIN2(w3_3);
    PIN2(b0p); PIN2(b1p); PIN2(b2p); PIN2(b3p);

    v2f y = (v2f){x0s[traj0 * N_D + o], x0s[traj1 * N_D + o]};

    if (lane16) {
        ybP[o] = y;
        out[(size_t)traj0 * N_T * N_D + o] = y.x;  // SaveAt includes t0
        out[(size_t)traj1 * N_T * N_D + o] = y.y;
    }

    auto EVAL = [&]() -> v2f {
        wave_fence();
        // L0: D=16 -> H=32, act-pair rows [t*8, t*8+8)
        const v4f* Y = reinterpret_cast<const v4f*>(ybP + t * 8);
        v4f u0 = Y[0], u1 = Y[1], u2 = Y[2], u3 = Y[3];
        v2f a0 = (v2f){0.f, 0.f}, a1 = (v2f){0.f, 0.f};
        PKFMA_LO(a0, lo2(u0), w0_0); PKFMA_HI(a1, hi2(u0), w0_0);
        PKFMA_LO(a0, lo2(u1), w0_1); PKFMA_HI(a1, hi2(u1), w0_1);
        PKFMA_LO(a0, lo2(u2), w0_2); PKFMA_HI(a1, hi2(u2), w0_2);
        PKFMA_LO(a0, lo2(u3), w0_3); PKFMA_HI(a1, hi2(u3), w0_3);
        v2f p = a0 + a1;
        v2f z = p + shxor(p, 32) + b0p;
        float zt = t ? z.y : z.x;
        ((float*)(AbP + j))[t] = softplus_f(zt);
        wave_fence();
        // L1: 32 -> 32, rows [t*16, t*16+16)
        const v4f* A = reinterpret_cast<const v4f*>(AbP + t * 16);
        v4f v0 = A[0], v1 = A[1], v2 = A[2], v3 = A[3];
        v4f v4 = A[4], v5 = A[5], v6 = A[6], v7 = A[7];
        a0 = (v2f){0.f, 0.f}; a1 = (v2f){0.f, 0.f};
        PKFMA_LO(a0, lo2(v0), w1_0); PKFMA_HI(a1, hi2(v0), w1_0);
        PKFMA_LO(a0, lo2(v1), w1_1); PKFMA_HI(a1, hi2(v1), w1_1);
        PKFMA_LO(a0, lo2(v2), w1_2); PKFMA_HI(a1, hi2(v2), w1_2);
        PKFMA_LO(a0, lo2(v3), w1_3); PKFMA_HI(a1, hi2(v3), w1_3);
        PKFMA_LO(a0, lo2(v4), w1_4); PKFMA_HI(a1, hi2(v4), w1_4);
        PKFMA_LO(a0, lo2(v5), w1_5); PKFMA_HI(a1, hi2(v5), w1_5);
        PKFMA_LO(a0, lo2(v6), w1_6); PKFMA_HI(a1, hi2(v6), w1_6);
        PKFMA_LO(a0, lo2(v7), w1_7); PKFMA_HI(a1, hi2(v7), w1_7);
        p = a0 + a1;
        z = p + shxor(p, 32) + b1p;
        zt = t ? z.y : z.x;
        ((float*)(BbP + j))[t] = softplus_f(zt);
        wave_fence();
        // L2: 32 -> 32
        const v4f* B = reinterpret_cast<const v4f*>(BbP + t * 16);
        v0 = B[0]; v1 = B[1]; v2 = B[2]; v3 = B[3];
        v4 = B[4]; v5 = B[5]; v6 = B[6]; v7 = B[7];
        a0 = (v2f){0.f, 0.f}; a1 = (v2f){0.f, 0.f};
        PKFMA_LO(a0, lo2(v0), w2_0); PKFMA_HI(a1, hi2(v0), w2_0);
        PKFMA_LO(a0, lo2(v1), w2_1); PKFMA_HI(a1, hi2(v1), w2_1);
        PKFMA_LO(a0, lo2(v2), w2_2); PKFMA_HI(a1, hi2(v2), w2_2);
        PKFMA_LO(a0, lo2(v3), w2_3); PKFMA_HI(a1, hi2(v3), w2_3);
        PKFMA_LO(a0, lo2(v4), w2_4); PKFMA_HI(a1, hi2(v4), w2_4);
        PKFMA_LO(a0, lo2(v5), w2_5); PKFMA_HI(a1, hi2(v5), w2_5);
        PKFMA_LO(a0, lo2(v6), w2_6); PKFMA_HI(a1, hi2(v6), w2_6);
        PKFMA_LO(a0, lo2(v7), w2_7); PKFMA_HI(a1, hi2(v7), w2_7);
        p = a0 + a1;
        z = p + shxor(p, 32) + b2p;
        zt = t ? z.y : z.x;
        ((float*)(AbP + j))[t] = softplus_f(zt);
        wave_fence();
        // L3: 32 -> 16, rows [h*16 + t*8, +8) of col o
        const v4f* C = reinterpret_cast<const v4f*>(AbP + h * 16 + t * 8);
        v4f c0 = C[0], c1 = C[1], c2 = C[2], c3 = C[3];
        a0 = (v2f){0.f, 0.f}; a1 = (v2f){0.f, 0.f};
        PKFMA_LO(a0, lo2(c0), w3_0); PKFMA_HI(a1, hi2(c0), w3_0);
        PKFMA_LO(a0, lo2(c1), w3_1); PKFMA_HI(a1, hi2(c1), w3_1);
        PKFMA_LO(a0, lo2(c2), w3_2); PKFMA_HI(a1, hi2(c2), w3_2);
        PKFMA_LO(a0, lo2(c3), w3_3); PKFMA_HI(a1, hi2(c3), w3_3);
        p = a0 + a1;
        p = p + shxor(p, 32);   // fold t-halves
        p = p + shxor(p, 16);   // fold h-halves
        return p + b3p;          // k pair {k_traj0, k_traj1} on all lanes
    };

    for (int ti = 0; ti < N_T - 1; ++ti) {
        const float dt = (t_eval[ti + 1] - t_eval[ti]) * 0.125f;  // / N_SUB

#pragma unroll 1
        for (int s = 0; s < 8; ++s) {
            const v2f k1 = EVAL();
            {
                v2f ys = vfmac(dt, vmulc(cA21, k1), y);
                if (lane16) ybP[o] = ys;
            }
            const v2f k2 = EVAL();
            {
                v2f a = vmulc(cA31, k1); a = vfmac(cA32, k2, a);
                v2f ys = vfmac(dt, a, y);
                if (lane16) ybP[o] = ys;
            }
            const v2f k3 = EVAL();
            {
                v2f a = vmulc(cA41, k1); a = vfmac(cA42, k2, a); a = vfmac(cA43, k3, a);
                v2f ys = vfmac(dt, a, y);
                if (lane16) ybP[o] = ys;
            }
            const v2f k4 = EVAL();
            {
                v2f a = vmulc(cA51, k1); a = vfmac(cA52, k2, a); a = vfmac(cA53, k3, a);
                a = vfmac(cA54, k4, a);
                v2f ys = vfmac(dt, a, y);
                if (lane16) ybP[o] = ys;
            }
            const v2f k5 = EVAL();
            {
                v2f a = vmulc(cA61, k1); a = vfmac(cA62, k2, a); a = vfmac(cA63, k3, a);
                a = vfmac(cA64, k4, a); a = vfmac(cA65, k5, a);
                v2f ys = vfmac(dt, a, y);
                if (lane16) ybP[o] = ys;
            }
            const v2f k6 = EVAL();
            {
                v2f a = vmulc(cB1, k1); a = vfmac(cB2, k2, a); a = vfmac(cB3, k3, a);
                a = vfmac(cB4, k4, a); a = vfmac(cB5, k5, a); a = vfmac(cB6, k6, a);
                y = vfmac(dt, a, y);
                if (lane16) ybP[o] = y;
            }
        }
        if (lane16) {
            out[((size_t)traj0 * N_T + (ti + 1)) * N_D + o] = y.x;
            out[((size_t)traj1 * N_T + (ti + 1)) * N_D + o] = y.y;
        }
    }
}

extern "C" void kernel_launch(void* const* d_in, const int* in_sizes, int n_in,
                              void* d_out, int out_size, void* d_ws, size_t ws_size,
                              hipStream_t stream) {
    const float* x0s    = (const float*)d_in[0];
    const float* t_eval = (const float*)d_in[1];
    const float* W0     = (const float*)d_in[2];
    const float* b0     = (const float*)d_in[3];
    const float* W1     = (const float*)d_in[4];
    const float* b1     = (const float*)d_in[5];
    const float* W2     = (const float*)d_in[6];
    const float* b2     = (const float*)d_in[7];
    const float* W3     = (const float*)d_in[8];
    const float* b3     = (const float*)d_in[9];
    float* out          = (float*)d_out;

    dim3 grid(N_B / 8);   // 4 waves/block x 2 trajectories/wave
    dim3 block(256);
    hipLaunchKernelGGL(ode_tsit5_kernel, grid, block, 0, stream,
                       x0s, t_eval, W0, b0, W1, b1, W2, b2, W3, b3, out);
}

// Round 11
// 2666.043 us; speedup vs baseline: 1.0067x; 1.0067x over previous
//
#include <hip/hip_runtime.h>

typedef float v2f __attribute__((ext_vector_type(2)));
typedef float v4f __attribute__((ext_vector_type(4)));

// Tsit5 coefficients (b7 = 0 -> 6 stages)
__device__ constexpr float cA21 = 0.161f;
__device__ constexpr float cA31 = -0.008480655492356989f, cA32 = 0.335480655492357f;
__device__ constexpr float cA41 = 2.8971530571054935f,  cA42 = -6.359448489975075f,  cA43 = 4.3622954328695815f;
__device__ constexpr float cA51 = 5.325864828439257f,   cA52 = -11.748883564062828f, cA53 = 7.4955393428898365f, cA54 = -0.09249506636175525f;
__device__ constexpr float cA61 = 5.86145544294642f,    cA62 = -12.92096931784711f,  cA63 = 8.159367898576159f,  cA64 = -0.071584973281401f, cA65 = -0.028269050394068383f;
__device__ constexpr float cB1 = 0.09646076681806523f,  cB2 = 0.01f,                 cB3 = 0.4798896504144996f;
__device__ constexpr float cB4 = 1.379008574103742f,    cB5 = -3.290069515436081f,   cB6 = 2.324710524099774f;

#define N_D 16
#define N_H 32
#define N_T 40
#define N_B 8192

// Round-10 evidence: dur was FLAT while MAC instrs halved => not issue-bound;
// bound by the 4x per-eval LDS round-trip chain (write -> s_waitcnt lgkmcnt(0)
// full drain -> read). All exchange is INTRA-wave (per-wave buffers), and DS
// ops of one wave are processed in order by the LDS pipe, so a read issued
// after a write in the same wave returns post-write data with no waitcnt.
// Keep only a COMPILER barrier (orders the memory ops, emits nothing); the
// data-arrival lgkmcnt(N) before first use is auto-inserted by the compiler.
__device__ __forceinline__ void compiler_fence() {
    asm volatile("" ::: "memory");
}

#define PIN2(v)  asm volatile("" : "+v"(v))

// Packed fp32 FMA (v_pk_fma_f32), weight broadcast via op_sel word select:
//  LO: d.{lo,hi} += a.{lo,hi} * w.word0 ; HI: ... * w.word1
#define PKFMA_LO(d,a,w) asm("v_pk_fma_f32 %0, %1, %2, %0 op_sel:[0,0,0] op_sel_hi:[1,0,1]" : "+v"(d) : "v"(a), "v"(w))
#define PKFMA_HI(d,a,w) asm("v_pk_fma_f32 %0, %1, %2, %0 op_sel:[0,1,0] op_sel_hi:[1,1,1]" : "+v"(d) : "v"(a), "v"(w))

__device__ __forceinline__ float softplus_f(float x) {
    float e = __expf(-fabsf(x));
    return fmaxf(x, 0.0f) + __logf(1.0f + e);
}

__device__ __forceinline__ v2f vmulc(float c, v2f a) { return (v2f){c * a.x, c * a.y}; }
__device__ __forceinline__ v2f vfmac(float c, v2f a, v2f b) {
    return (v2f){fmaf(c, a.x, b.x), fmaf(c, a.y, b.y)};
}
__device__ __forceinline__ v2f shxor(v2f v, int m) {
    v2f r; r.x = __shfl_xor(v.x, m, 64); r.y = __shfl_xor(v.y, m, 64); return r;
}
__device__ __forceinline__ v2f lo2(v4f u) { return __builtin_shufflevector(u, u, 0, 1); }
__device__ __forceinline__ v2f hi2(v4f u) { return __builtin_shufflevector(u, u, 2, 3); }

// Wave = 64 lanes = 2 trajectories (v2f pairs) x 32 neurons. 48 VGPRs of
// weights/lane (row-half of each column as float2 row-pairs, op_sel broadcast).
// A/B activation buffers carry a 64B pad between the t-halves: round-10 PMC
// showed 4.6e7 bank-conflict cycles because bytes [0,128) and [128,256) hit
// the same banks for the two half-wave broadcast reads. Padded slot/base
// offsets are loop-invariant (jw = j + (j>>4)*8; read base t*24 / h*24+t*8).
#define PADH 8   // 8 v2f pairs = 64B pad between halves
__global__ void __launch_bounds__(256)
__attribute__((amdgpu_waves_per_eu(4, 4)))
ode_tsit5_kernel(
    const float* __restrict__ x0s, const float* __restrict__ t_eval,
    const float* __restrict__ W0, const float* __restrict__ b0,
    const float* __restrict__ W1, const float* __restrict__ b1,
    const float* __restrict__ W2, const float* __restrict__ b2,
    const float* __restrict__ W3, const float* __restrict__ b3,
    float* __restrict__ out)
{
    __shared__ alignas(16) v2f ybufP[4][N_D];            // halves already bank-disjoint
    __shared__ alignas(16) v2f AbufP[4][N_H + PADH];
    __shared__ alignas(16) v2f BbufP[4][N_H + PADH];

    const int tid  = threadIdx.x;
    const int wid  = tid >> 6;
    const int lane = tid & 63;
    const int t    = lane >> 5;   // row-half owned / pair-word extracted
    const int j    = lane & 31;   // neuron / column index
    const int o    = j & 15;      // state dim (layers 0 and 3)
    const int h    = j >> 4;      // 16-row half of W3 covered
    const int traj0 = (blockIdx.x * 4 + wid) * 2;
    const int traj1 = traj0 + 1;
    const bool lane16 = (lane < 16);
    const int jw = j + ((j >> 4) << 3);      // padded write slot (loop-invariant)
    const int rbase = t * (16 + PADH);       // padded L1/L2 read base (pairs)
    const int r3base = h * (16 + PADH) + t * 8;  // padded L3 read base

    v2f* ybP = ybufP[wid];
    v2f* AbP = AbufP[wid];
    v2f* BbP = BbufP[wid];

    // Weight row-pairs: w*_q = {W[row 2q], W[row 2q+1]} of this lane's column.
    v2f w0_0, w0_1, w0_2, w0_3;
    v2f w1_0, w1_1, w1_2, w1_3, w1_4, w1_5, w1_6, w1_7;
    v2f w2_0, w2_1, w2_2, w2_3, w2_4, w2_5, w2_6, w2_7;
    v2f w3_0, w3_1, w3_2, w3_3;
#define LDW(dst, Wp, r0, col, LD) dst = (v2f){Wp[(r0) * LD + (col)], Wp[((r0) + 1) * LD + (col)]}
    LDW(w0_0, W0, t * 8 + 0, j, N_H); LDW(w0_1, W0, t * 8 + 2, j, N_H);
    LDW(w0_2, W0, t * 8 + 4, j, N_H); LDW(w0_3, W0, t * 8 + 6, j, N_H);
    LDW(w1_0, W1, t * 16 + 0,  j, N_H); LDW(w1_1, W1, t * 16 + 2,  j, N_H);
    LDW(w1_2, W1, t * 16 + 4,  j, N_H); LDW(w1_3, W1, t * 16 + 6,  j, N_H);
    LDW(w1_4, W1, t * 16 + 8,  j, N_H); LDW(w1_5, W1, t * 16 + 10, j, N_H);
    LDW(w1_6, W1, t * 16 + 12, j, N_H); LDW(w1_7, W1, t * 16 + 14, j, N_H);
    LDW(w2_0, W2, t * 16 + 0,  j, N_H); LDW(w2_1, W2, t * 16 + 2,  j, N_H);
    LDW(w2_2, W2, t * 16 + 4,  j, N_H); LDW(w2_3, W2, t * 16 + 6,  j, N_H);
    LDW(w2_4, W2, t * 16 + 8,  j, N_H); LDW(w2_5, W2, t * 16 + 10, j, N_H);
    LDW(w2_6, W2, t * 16 + 12, j, N_H); LDW(w2_7, W2, t * 16 + 14, j, N_H);
    LDW(w3_0, W3, h * 16 + t * 8 + 0, o, N_D); LDW(w3_1, W3, h * 16 + t * 8 + 2, o, N_D);
    LDW(w3_2, W3, h * 16 + t * 8 + 4, o, N_D); LDW(w3_3, W3, h * 16 + t * 8 + 6, o, N_D);
#undef LDW
    v2f b0p = (v2f){b0[j], b0[j]};
    v2f b1p = (v2f){b1[j], b1[j]};
    v2f b2p = (v2f){b2[j], b2[j]};
    v2f b3p = (v2f){b3[o], b3[o]};

    PIN2(w0_0); PIN2(w0_1); PIN2(w0_2); PIN2(w0_3);
    PIN2(w1_0); PIN2(w1_1); PIN2(w1_2); PIN2(w1_3);
    PIN2(w1_4); PIN2(w1_5); PIN2(w1_6); PIN2(w1_7);
    PIN2(w2_0); PIN2(w2_1); PIN2(w2_2); PIN2(w2_3);
    PIN2(w2_4); PIN2(w2_5); PIN2(w2_6); PIN2(w2_7);
    PIN2(w3_0); PIN2(w3_1); PIN2(w3_2); PIN2(w3_3);
    PIN2(b0p); PIN2(b1p); PIN2(b2p); PIN2(b3p);

    v2f y = (v2f){x0s[traj0 * N_D + o], x0s[traj1 * N_D + o]};

    if (lane16) {
        ybP[o] = y;
        out[(size_t)traj0 * N_T * N_D + o] = y.x;  // SaveAt includes t0
        out[(size_t)traj1 * N_T * N_D + o] = y.y;
    }

    auto EVAL = [&]() -> v2f {
        compiler_fence();
        // L0: D=16 -> H=32, act-pair rows [t*8, t*8+8) (halves bank-disjoint)
        const v4f* Y = reinterpret_cast<const v4f*>(ybP + t * 8);
        v4f u0 = Y[0], u1 = Y[1], u2 = Y[2], u3 = Y[3];
        v2f a0 = (v2f){0.f, 0.f}, a1 = (v2f){0.f, 0.f};
        PKFMA_LO(a0, lo2(u0), w0_0); PKFMA_HI(a1, hi2(u0), w0_0);
        PKFMA_LO(a0, lo2(u1), w0_1); PKFMA_HI(a1, hi2(u1), w0_1);
        PKFMA_LO(a0, lo2(u2), w0_2); PKFMA_HI(a1, hi2(u2), w0_2);
        PKFMA_LO(a0, lo2(u3), w0_3); PKFMA_HI(a1, hi2(u3), w0_3);
        v2f p = a0 + a1;
        v2f z = p + shxor(p, 32) + b0p;
        float zt = t ? z.y : z.x;
        ((float*)(AbP + jw))[t] = softplus_f(zt);
        compiler_fence();
        // L1: 32 -> 32, rows [t*16, +16) -> padded base rbase
        const v4f* A = reinterpret_cast<const v4f*>(AbP + rbase);
        v4f v0 = A[0], v1 = A[1], v2 = A[2], v3 = A[3];
        v4f v4 = A[4], v5 = A[5], v6 = A[6], v7 = A[7];
        a0 = (v2f){0.f, 0.f}; a1 = (v2f){0.f, 0.f};
        PKFMA_LO(a0, lo2(v0), w1_0); PKFMA_HI(a1, hi2(v0), w1_0);
        PKFMA_LO(a0, lo2(v1), w1_1); PKFMA_HI(a1, hi2(v1), w1_1);
        PKFMA_LO(a0, lo2(v2), w1_2); PKFMA_HI(a1, hi2(v2), w1_2);
        PKFMA_LO(a0, lo2(v3), w1_3); PKFMA_HI(a1, hi2(v3), w1_3);
        PKFMA_LO(a0, lo2(v4), w1_4); PKFMA_HI(a1, hi2(v4), w1_4);
        PKFMA_LO(a0, lo2(v5), w1_5); PKFMA_HI(a1, hi2(v5), w1_5);
        PKFMA_LO(a0, lo2(v6), w1_6); PKFMA_HI(a1, hi2(v6), w1_6);
        PKFMA_LO(a0, lo2(v7), w1_7); PKFMA_HI(a1, hi2(v7), w1_7);
        p = a0 + a1;
        z = p + shxor(p, 32) + b1p;
        zt = t ? z.y : z.x;
        ((float*)(BbP + jw))[t] = softplus_f(zt);
        compiler_fence();
        // L2: 32 -> 32
        const v4f* B = reinterpret_cast<const v4f*>(BbP + rbase);
        v0 = B[0]; v1 = B[1]; v2 = B[2]; v3 = B[3];
        v4 = B[4]; v5 = B[5]; v6 = B[6]; v7 = B[7];
        a0 = (v2f){0.f, 0.f}; a1 = (v2f){0.f, 0.f};
        PKFMA_LO(a0, lo2(v0), w2_0); PKFMA_HI(a1, hi2(v0), w2_0);
        PKFMA_LO(a0, lo2(v1), w2_1); PKFMA_HI(a1, hi2(v1), w2_1);
        PKFMA_LO(a0, lo2(v2), w2_2); PKFMA_HI(a1, hi2(v2), w2_2);
        PKFMA_LO(a0, lo2(v3), w2_3); PKFMA_HI(a1, hi2(v3), w2_3);
        PKFMA_LO(a0, lo2(v4), w2_4); PKFMA_HI(a1, hi2(v4), w2_4);
        PKFMA_LO(a0, lo2(v5), w2_5); PKFMA_HI(a1, hi2(v5), w2_5);
        PKFMA_LO(a0, lo2(v6), w2_6); PKFMA_HI(a1, hi2(v6), w2_6);
        PKFMA_LO(a0, lo2(v7), w2_7); PKFMA_HI(a1, hi2(v7), w2_7);
        p = a0 + a1;
        z = p + shxor(p, 32) + b2p;
        zt = t ? z.y : z.x;
        ((float*)(AbP + jw))[t] = softplus_f(zt);
        compiler_fence();
        // L3: 32 -> 16, padded base r3base
        const v4f* C = reinterpret_cast<const v4f*>(AbP + r3base);
        v4f c0 = C[0], c1 = C[1], c2 = C[2], c3 = C[3];
        a0 = (v2f){0.f, 0.f}; a1 = (v2f){0.f, 0.f};
        PKFMA_LO(a0, lo2(c0), w3_0); PKFMA_HI(a1, hi2(c0), w3_0);
        PKFMA_LO(a0, lo2(c1), w3_1); PKFMA_HI(a1, hi2(c1), w3_1);
        PKFMA_LO(a0, lo2(c2), w3_2); PKFMA_HI(a1, hi2(c2), w3_2);
        PKFMA_LO(a0, lo2(c3), w3_3); PKFMA_HI(a1, hi2(c3), w3_3);
        p = a0 + a1;
        p = p + shxor(p, 32);   // fold t-halves
        p = p + shxor(p, 16);   // fold h-halves
        return p + b3p;          // k pair {k_traj0, k_traj1} on all lanes
    };

    for (int ti = 0; ti < N_T - 1; ++ti) {
        const float dt = (t_eval[ti + 1] - t_eval[ti]) * 0.125f;  // / N_SUB

#pragma unroll 1
        for (int s = 0; s < 8; ++s) {
            const v2f k1 = EVAL();
            {
                v2f ys = vfmac(dt, vmulc(cA21, k1), y);
                if (lane16) ybP[o] = ys;
            }
            const v2f k2 = EVAL();
            {
                v2f a = vmulc(cA31, k1); a = vfmac(cA32, k2, a);
                v2f ys = vfmac(dt, a, y);
                if (lane16) ybP[o] = ys;
            }
            const v2f k3 = EVAL();
            {
                v2f a = vmulc(cA41, k1); a = vfmac(cA42, k2, a); a = vfmac(cA43, k3, a);
                v2f ys = vfmac(dt, a, y);
                if (lane16) ybP[o] = ys;
            }
            const v2f k4 = EVAL();
            {
                v2f a = vmulc(cA51, k1); a = vfmac(cA52, k2, a); a = vfmac(cA53, k3, a);
                a = vfmac(cA54, k4, a);
                v2f ys = vfmac(dt, a, y);
                if (lane16) ybP[o] = ys;
            }
            const v2f k5 = EVAL();
            {
                v2f a = vmulc(cA61, k1); a = vfmac(cA62, k2, a); a = vfmac(cA63, k3, a);
                a = vfmac(cA64, k4, a); a = vfmac(cA65, k5, a);
                v2f ys = vfmac(dt, a, y);
                if (lane16) ybP[o] = ys;
            }
            const v2f k6 = EVAL();
            {
                v2f a = vmulc(cB1, k1); a = vfmac(cB2, k2, a); a = vfmac(cB3, k3, a);
                a = vfmac(cB4, k4, a); a = vfmac(cB5, k5, a); a = vfmac(cB6, k6, a);
                y = vfmac(dt, a, y);
                if (lane16) ybP[o] = y;
            }
        }
        if (lane16) {
            out[((size_t)traj0 * N_T + (ti + 1)) * N_D + o] = y.x;
            out[((size_t)traj1 * N_T + (ti + 1)) * N_D + o] = y.y;
        }
    }
}

extern "C" void kernel_launch(void* const* d_in, const int* in_sizes, int n_in,
                              void* d_out, int out_size, void* d_ws, size_t ws_size,
                              hipStream_t stream) {
    const float* x0s    = (const float*)d_in[0];
    const float* t_eval = (const float*)d_in[1];
    const float* W0     = (const float*)d_in[2];
    const float* b0     = (const float*)d_in[3];
    const float* W1     = (const float*)d_in[4];
    const float* b1     = (const float*)d_in[5];
    const float* W2     = (const float*)d_in[6];
    const float* b2     = (const float*)d_in[7];
    const float* W3     = (const float*)d_in[8];
    const float* b3     = (const float*)d_in[9];
    float* out          = (float*)d_out;

    dim3 grid(N_B / 8);   // 4 waves/block x 2 trajectories/wave
    dim3 block(256);
    hipLaunchKernelGGL(ode_tsit5_kernel, grid, block, 0, stream,
                       x0s, t_eval, W0, b0, W1, b1, W2, b2, W3, b3, out);
}

// Round 12
// 2080.693 us; speedup vs baseline: 1.2899x; 1.2813x over previous
//
#include <hip/hip_runtime.h>

typedef float v2f __attribute__((ext_vector_type(2)));
typedef float v4f __attribute__((ext_vector_type(4)));

// Tsit5 coefficients (b7 = 0 -> 6 stages)
__device__ constexpr float cA21 = 0.161f;
__device__ constexpr float cA31 = -0.008480655492356989f, cA32 = 0.335480655492357f;
__device__ constexpr float cA41 = 2.8971530571054935f,  cA42 = -6.359448489975075f,  cA43 = 4.3622954328695815f;
__device__ constexpr float cA51 = 5.325864828439257f,   cA52 = -11.748883564062828f, cA53 = 7.4955393428898365f, cA54 = -0.09249506636175525f;
__device__ constexpr float cA61 = 5.86145544294642f,    cA62 = -12.92096931784711f,  cA63 = 8.159367898576159f,  cA64 = -0.071584973281401f, cA65 = -0.028269050394068383f;
__device__ constexpr float cB1 = 0.09646076681806523f,  cB2 = 0.01f,                 cB3 = 0.4798896504144996f;
__device__ constexpr float cB4 = 1.379008574103742f,    cB5 = -3.290069515436081f,   cB6 = 2.324710524099774f;

#define N_D 16
#define N_H 32
#define N_T 40
#define N_B 8192

// Order LDS ops without emitting waits: same-wave DS ops execute in issue
// order (validated rounds 10-11); compiler auto-inserts data-arrival waits.
__device__ __forceinline__ void compiler_fence() { asm volatile("" ::: "memory"); }
#define PIN2(v)  asm volatile("" : "+v"(v))

// Packed fp32 FMA, weight word-broadcast via op_sel (validated rounds 8-11):
//  LO: d += a * w.word0 ; HI: d += a * w.word1
#define PKFMA_LO(d,a,w) asm("v_pk_fma_f32 %0, %1, %2, %0 op_sel:[0,0,0] op_sel_hi:[1,0,1]" : "+v"(d) : "v"(a), "v"(w))
#define PKFMA_HI(d,a,w) asm("v_pk_fma_f32 %0, %1, %2, %0 op_sel:[0,1,0] op_sel_hi:[1,1,1]" : "+v"(d) : "v"(a), "v"(w))

// s[l] = a[l] + a[l^32] via v_permlane32_swap (VALU pipe — replaces the
// ds_bpermute-based __shfl_xor that was loading the saturated LDS pipe).
// After swap with b=c=a: {b,c} = {lo-replicated, hi-replicated} (in either
// operand order), so b+c is the xor-32 sum on every lane — direction-proof.
__device__ __forceinline__ float xor32_sum1(float a) {
    float b = a, c = a;
    asm("v_permlane32_swap_b32 %0, %1" : "+v"(b), "+v"(c));
    return b + c;
}
__device__ __forceinline__ v2f xor32_sum2(v2f a) {
    v2f r; r.x = xor32_sum1(a.x); r.y = xor32_sum1(a.y); return r;
}

__device__ __forceinline__ float softplus_f(float x) {
    float e = __expf(-fabsf(x));
    return fmaxf(x, 0.0f) + __logf(1.0f + e);
}
__device__ __forceinline__ v2f softplus2(v2f z) {
    v2f r; r.x = softplus_f(z.x); r.y = softplus_f(z.y); return r;
}
__device__ __forceinline__ v2f vmulc(float c, v2f a) { return (v2f){c * a.x, c * a.y}; }
__device__ __forceinline__ v2f vfmac(float c, v2f a, v2f b) {
    return (v2f){fmaf(c, a.x, b.x), fmaf(c, a.y, b.y)};
}
__device__ __forceinline__ v2f lo2(v4f u) { return __builtin_shufflevector(u, u, 0, 1); }
__device__ __forceinline__ v2f hi2(v4f u) { return __builtin_shufflevector(u, u, 2, 3); }

// Wave = 64 lanes = 4 trajectories x 32 neurons with 2-way neuron blocking:
// lane (kh=l>>5, q=(l>>4)&1, i=l&15) computes neurons {i, i+16} of traj-pair q
// over k-half kh. Each activation pair read from LDS feeds TWO pk_fmas
// (round-11 diagnosis: LDS-pipe throughput bound; this halves read traffic
// per trajectory: 28 b128/wave for 4 traj vs 24 for 2). kh-halves combine via
// permlane32_swap on the VALU pipe. Row pads (+2 pairs) put the four
// broadcast-read base addresses in disjoint bank windows.
__global__ void __launch_bounds__(256)
__attribute__((amdgpu_waves_per_eu(2, 2)))
ode_tsit5_kernel(
    const float* __restrict__ x0s, const float* __restrict__ t_eval,
    const float* __restrict__ W0, const float* __restrict__ b0,
    const float* __restrict__ W1, const float* __restrict__ b1,
    const float* __restrict__ W2, const float* __restrict__ b2,
    const float* __restrict__ W3, const float* __restrict__ b3,
    float* __restrict__ out)
{
    __shared__ alignas(16) v2f ybS[4][2][2][10];   // [wave][q][half][8+2]
    __shared__ alignas(16) v2f AbS[4][2][2][18];   // [wave][q][kh][16+2]
    __shared__ alignas(16) v2f BbS[4][2][2][18];

    const int tid  = threadIdx.x;
    const int wid  = tid >> 6;
    const int lane = tid & 63;
    const int kh   = lane >> 5;        // k-half owned
    const int q    = (lane >> 4) & 1;  // trajectory-pair index within wave
    const int i    = lane & 15;        // neuron-group / output index
    const int n    = i + kh * 16;      // my write-neuron (mid layers)
    const int nx   = n ^ 16;           // partner neuron
    const int T    = (blockIdx.x * 4 + wid) * 4;
    const int tA   = T + q * 2, tB = tA + 1;

    v2f* pA = &AbS[wid][q][kh][i];
    v2f* pB = &BbS[wid][q][kh][i];
    v2f* pY = &ybS[wid][q][i >> 3][i & 7];
    const v4f* rY = reinterpret_cast<const v4f*>(&ybS[wid][q][kh][0]);
    const v4f* rA = reinterpret_cast<const v4f*>(&AbS[wid][q][kh][0]);
    const v4f* rB = reinterpret_cast<const v4f*>(&BbS[wid][q][kh][0]);

    // Weight fragments: mid layers store {W[r][n], W[r][nx]} per row (word0 =
    // my neuron, word1 = partner); L3 stores row-pairs of column i.
#define WCOL(Wp, R) (v2f){Wp[(R) * N_H + n], Wp[(R) * N_H + nx]}
    v2f w0p_0 = WCOL(W0, kh*8+0), w0p_1 = WCOL(W0, kh*8+1), w0p_2 = WCOL(W0, kh*8+2), w0p_3 = WCOL(W0, kh*8+3);
    v2f w0p_4 = WCOL(W0, kh*8+4), w0p_5 = WCOL(W0, kh*8+5), w0p_6 = WCOL(W0, kh*8+6), w0p_7 = WCOL(W0, kh*8+7);
    v2f w1p_0 = WCOL(W1, kh*16+0),  w1p_1 = WCOL(W1, kh*16+1),  w1p_2  = WCOL(W1, kh*16+2),  w1p_3  = WCOL(W1, kh*16+3);
    v2f w1p_4 = WCOL(W1, kh*16+4),  w1p_5 = WCOL(W1, kh*16+5),  w1p_6  = WCOL(W1, kh*16+6),  w1p_7  = WCOL(W1, kh*16+7);
    v2f w1p_8 = WCOL(W1, kh*16+8),  w1p_9 = WCOL(W1, kh*16+9),  w1p_10 = WCOL(W1, kh*16+10), w1p_11 = WCOL(W1, kh*16+11);
    v2f w1p_12 = WCOL(W1, kh*16+12), w1p_13 = WCOL(W1, kh*16+13), w1p_14 = WCOL(W1, kh*16+14), w1p_15 = WCOL(W1, kh*16+15);
    v2f w2p_0 = WCOL(W2, kh*16+0),  w2p_1 = WCOL(W2, kh*16+1),  w2p_2  = WCOL(W2, kh*16+2),  w2p_3  = WCOL(W2, kh*16+3);
    v2f w2p_4 = WCOL(W2, kh*16+4),  w2p_5 = WCOL(W2, kh*16+5),  w2p_6  = WCOL(W2, kh*16+6),  w2p_7  = WCOL(W2, kh*16+7);
    v2f w2p_8 = WCOL(W2, kh*16+8),  w2p_9 = WCOL(W2, kh*16+9),  w2p_10 = WCOL(W2, kh*16+10), w2p_11 = WCOL(W2, kh*16+11);
    v2f w2p_12 = WCOL(W2, kh*16+12), w2p_13 = WCOL(W2, kh*16+13), w2p_14 = WCOL(W2, kh*16+14), w2p_15 = WCOL(W2, kh*16+15);
#undef WCOL
#define W3PAIR(M) (v2f){W3[(kh*16 + 2*(M)) * N_D + i], W3[(kh*16 + 2*(M) + 1) * N_D + i]}
    v2f w3p_0 = W3PAIR(0), w3p_1 = W3PAIR(1), w3p_2 = W3PAIR(2), w3p_3 = W3PAIR(3);
    v2f w3p_4 = W3PAIR(4), w3p_5 = W3PAIR(5), w3p_6 = W3PAIR(6), w3p_7 = W3PAIR(7);
#undef W3PAIR
    v2f bn0 = (v2f){b0[n], b0[n]};
    v2f bn1 = (v2f){b1[n], b1[n]};
    v2f bn2 = (v2f){b2[n], b2[n]};
    v2f b3p = (v2f){b3[i], b3[i]};

    PIN2(w0p_0); PIN2(w0p_1); PIN2(w0p_2); PIN2(w0p_3);
    PIN2(w0p_4); PIN2(w0p_5); PIN2(w0p_6); PIN2(w0p_7);
    PIN2(w1p_0); PIN2(w1p_1); PIN2(w1p_2); PIN2(w1p_3);
    PIN2(w1p_4); PIN2(w1p_5); PIN2(w1p_6); PIN2(w1p_7);
    PIN2(w1p_8); PIN2(w1p_9); PIN2(w1p_10); PIN2(w1p_11);
    PIN2(w1p_12); PIN2(w1p_13); PIN2(w1p_14); PIN2(w1p_15);
    PIN2(w2p_0); PIN2(w2p_1); PIN2(w2p_2); PIN2(w2p_3);
    PIN2(w2p_4); PIN2(w2p_5); PIN2(w2p_6); PIN2(w2p_7);
    PIN2(w2p_8); PIN2(w2p_9); PIN2(w2p_10); PIN2(w2p_11);
    PIN2(w2p_12); PIN2(w2p_13); PIN2(w2p_14); PIN2(w2p_15);
    PIN2(w3p_0); PIN2(w3p_1); PIN2(w3p_2); PIN2(w3p_3);
    PIN2(w3p_4); PIN2(w3p_5); PIN2(w3p_6); PIN2(w3p_7);
    PIN2(bn0); PIN2(bn1); PIN2(bn2); PIN2(b3p);

    v2f y = (v2f){x0s[tA * N_D + i], x0s[tB * N_D + i]};

    if (!kh) {
        *pY = y;
        out[(size_t)tA * N_T * N_D + i] = y.x;  // SaveAt includes t0
        out[(size_t)tB * N_T * N_D + i] = y.y;
    }

    auto EVAL = [&]() -> v2f {
        compiler_fence();
        // L0: D=16 -> H=32, k-rows [kh*8, kh*8+8)
        v4f u0 = rY[0], u1 = rY[1], u2 = rY[2], u3 = rY[3];
        v2f aA = (v2f){0.f, 0.f}, aB = (v2f){0.f, 0.f};
        PKFMA_LO(aA, lo2(u0), w0p_0); PKFMA_HI(aB, lo2(u0), w0p_0);
        PKFMA_LO(aA, hi2(u0), w0p_1); PKFMA_HI(aB, hi2(u0), w0p_1);
        PKFMA_LO(aA, lo2(u1), w0p_2); PKFMA_HI(aB, lo2(u1), w0p_2);
        PKFMA_LO(aA, hi2(u1), w0p_3); PKFMA_HI(aB, hi2(u1), w0p_3);
        PKFMA_LO(aA, lo2(u2), w0p_4); PKFMA_HI(aB, lo2(u2), w0p_4);
        PKFMA_LO(aA, hi2(u2), w0p_5); PKFMA_HI(aB, hi2(u2), w0p_5);
        PKFMA_LO(aA, lo2(u3), w0p_6); PKFMA_HI(aB, lo2(u3), w0p_6);
        PKFMA_LO(aA, hi2(u3), w0p_7); PKFMA_HI(aB, hi2(u3), w0p_7);
        // full z for MY neuron n = aA + partner's aB = aA - aB + xor32sum(aB)
        v2f z = aA - aB + xor32_sum2(aB) + bn0;
        *pA = softplus2(z);
        compiler_fence();
        // L1: 32 -> 32, k-rows [kh*16, +16)
        v4f m0 = rA[0], m1 = rA[1], m2 = rA[2], m3 = rA[3];
        v4f m4 = rA[4], m5 = rA[5], m6 = rA[6], m7 = rA[7];
        aA = (v2f){0.f, 0.f}; aB = (v2f){0.f, 0.f};
        PKFMA_LO(aA, lo2(m0), w1p_0);  PKFMA_HI(aB, lo2(m0), w1p_0);
        PKFMA_LO(aA, hi2(m0), w1p_1);  PKFMA_HI(aB, hi2(m0), w1p_1);
        PKFMA_LO(aA, lo2(m1), w1p_2);  PKFMA_HI(aB, lo2(m1), w1p_2);
        PKFMA_LO(aA, hi2(m1), w1p_3);  PKFMA_HI(aB, hi2(m1), w1p_3);
        PKFMA_LO(aA, lo2(m2), w1p_4);  PKFMA_HI(aB, lo2(m2), w1p_4);
        PKFMA_LO(aA, hi2(m2), w1p_5);  PKFMA_HI(aB, hi2(m2), w1p_5);
        PKFMA_LO(aA, lo2(m3), w1p_6);  PKFMA_HI(aB, lo2(m3), w1p_6);
        PKFMA_LO(aA, hi2(m3), w1p_7);  PKFMA_HI(aB, hi2(m3), w1p_7);
        PKFMA_LO(aA, lo2(m4), w1p_8);  PKFMA_HI(aB, lo2(m4), w1p_8);
        PKFMA_LO(aA, hi2(m4), w1p_9);  PKFMA_HI(aB, hi2(m4), w1p_9);
        PKFMA_LO(aA, lo2(m5), w1p_10); PKFMA_HI(aB, lo2(m5), w1p_10);
        PKFMA_LO(aA, hi2(m5), w1p_11); PKFMA_HI(aB, hi2(m5), w1p_11);
        PKFMA_LO(aA, lo2(m6), w1p_12); PKFMA_HI(aB, lo2(m6), w1p_12);
        PKFMA_LO(aA, hi2(m6), w1p_13); PKFMA_HI(aB, hi2(m6), w1p_13);
        PKFMA_LO(aA, lo2(m7), w1p_14); PKFMA_HI(aB, lo2(m7), w1p_14);
        PKFMA_LO(aA, hi2(m7), w1p_15); PKFMA_HI(aB, hi2(m7), w1p_15);
        z = aA - aB + xor32_sum2(aB) + bn1;
        *pB = softplus2(z);
        compiler_fence();
        // L2: 32 -> 32
        m0 = rB[0]; m1 = rB[1]; m2 = rB[2]; m3 = rB[3];
        m4 = rB[4]; m5 = rB[5]; m6 = rB[6]; m7 = rB[7];
        aA = (v2f){0.f, 0.f}; aB = (v2f){0.f, 0.f};
        PKFMA_LO(aA, lo2(m0), w2p_0);  PKFMA_HI(aB, lo2(m0), w2p_0);
        PKFMA_LO(aA, hi2(m0), w2p_1);  PKFMA_HI(aB, hi2(m0), w2p_1);
        PKFMA_LO(aA, lo2(m1), w2p_2);  PKFMA_HI(aB, lo2(m1), w2p_2);
        PKFMA_LO(aA, hi2(m1), w2p_3);  PKFMA_HI(aB, hi2(m1), w2p_3);
        PKFMA_LO(aA, lo2(m2), w2p_4);  PKFMA_HI(aB, lo2(m2), w2p_4);
        PKFMA_LO(aA, hi2(m2), w2p_5);  PKFMA_HI(aB, hi2(m2), w2p_5);
        PKFMA_LO(aA, lo2(m3), w2p_6);  PKFMA_HI(aB, lo2(m3), w2p_6);
        PKFMA_LO(aA, hi2(m3), w2p_7);  PKFMA_HI(aB, hi2(m3), w2p_7);
        PKFMA_LO(aA, lo2(m4), w2p_8);  PKFMA_HI(aB, lo2(m4), w2p_8);
        PKFMA_LO(aA, hi2(m4), w2p_9);  PKFMA_HI(aB, hi2(m4), w2p_9);
        PKFMA_LO(aA, lo2(m5), w2p_10); PKFMA_HI(aB, lo2(m5), w2p_10);
        PKFMA_LO(aA, hi2(m5), w2p_11); PKFMA_HI(aB, hi2(m5), w2p_11);
        PKFMA_LO(aA, lo2(m6), w2p_12); PKFMA_HI(aB, lo2(m6), w2p_12);
        PKFMA_LO(aA, hi2(m6), w2p_13); PKFMA_HI(aB, hi2(m6), w2p_13);
        PKFMA_LO(aA, lo2(m7), w2p_14); PKFMA_HI(aB, lo2(m7), w2p_14);
        PKFMA_LO(aA, hi2(m7), w2p_15); PKFMA_HI(aB, hi2(m7), w2p_15);
        z = aA - aB + xor32_sum2(aB) + bn2;
        *pA = softplus2(z);
        compiler_fence();
        // L3: 32 -> 16, output i, k-rows [kh*16, +16); row-pairs via LO/HI
        v4f c0 = rA[0], c1 = rA[1], c2 = rA[2], c3 = rA[3];
        v4f c4 = rA[4], c5 = rA[5], c6 = rA[6], c7 = rA[7];
        aA = (v2f){0.f, 0.f}; aB = (v2f){0.f, 0.f};
        PKFMA_LO(aA, lo2(c0), w3p_0); PKFMA_HI(aB, hi2(c0), w3p_0);
        PKFMA_LO(aA, lo2(c1), w3p_1); PKFMA_HI(aB, hi2(c1), w3p_1);
        PKFMA_LO(aA, lo2(c2), w3p_2); PKFMA_HI(aB, hi2(c2), w3p_2);
        PKFMA_LO(aA, lo2(c3), w3p_3); PKFMA_HI(aB, hi2(c3), w3p_3);
        PKFMA_LO(aA, lo2(c4), w3p_4); PKFMA_HI(aB, hi2(c4), w3p_4);
        PKFMA_LO(aA, lo2(c5), w3p_5); PKFMA_HI(aB, hi2(c5), w3p_5);
        PKFMA_LO(aA, lo2(c6), w3p_6); PKFMA_HI(aB, hi2(c6), w3p_6);
        PKFMA_LO(aA, lo2(c7), w3p_7); PKFMA_HI(aB, hi2(c7), w3p_7);
        v2f p = aA + aB;                 // my k-half partial of k[i]
        return xor32_sum2(p) + b3p;      // + partner half -> full k[i] pair
    };

    for (int ti = 0; ti < N_T - 1; ++ti) {
        const float dt = (t_eval[ti + 1] - t_eval[ti]) * 0.125f;  // / N_SUB

#pragma unroll 1
        for (int s = 0; s < 8; ++s) {
            const v2f k1 = EVAL();
            {
                v2f ys = vfmac(dt, vmulc(cA21, k1), y);
                if (!kh) *pY = ys;
            }
            const v2f k2 = EVAL();
            {
                v2f a = vmulc(cA31, k1); a = vfmac(cA32, k2, a);
                v2f ys = vfmac(dt, a, y);
                if (!kh) *pY = ys;
            }
            const v2f k3 = EVAL();
            {
                v2f a = vmulc(cA41, k1); a = vfmac(cA42, k2, a); a = vfmac(cA43, k3, a);
                v2f ys = vfmac(dt, a, y);
                if (!kh) *pY = ys;
            }
            const v2f k4 = EVAL();
            {
                v2f a = vmulc(cA51, k1); a = vfmac(cA52, k2, a); a = vfmac(cA53, k3, a);
                a = vfmac(cA54, k4, a);
                v2f ys = vfmac(dt, a, y);
                if (!kh) *pY = ys;
            }
            const v2f k5 = EVAL();
            {
                v2f a = vmulc(cA61, k1); a = vfmac(cA62, k2, a); a = vfmac(cA63, k3, a);
                a = vfmac(cA64, k4, a); a = vfmac(cA65, k5, a);
                v2f ys = vfmac(dt, a, y);
                if (!kh) *pY = ys;
            }
            const v2f k6 = EVAL();
            {
                v2f a = vmulc(cB1, k1); a = vfmac(cB2, k2, a); a = vfmac(cB3, k3, a);
                a = vfmac(cB4, k4, a); a = vfmac(cB5, k5, a); a = vfmac(cB6, k6, a);
                y = vfmac(dt, a, y);
                if (!kh) *pY = y;
            }
        }
        if (!kh) {
            out[((size_t)tA * N_T + (ti + 1)) * N_D + i] = y.x;
            out[((size_t)tB * N_T + (ti + 1)) * N_D + i] = y.y;
        }
    }
}

extern "C" void kernel_launch(void* const* d_in, const int* in_sizes, int n_in,
                              void* d_out, int out_size, void* d_ws, size_t ws_size,
                              hipStream_t stream) {
    const float* x0s    = (const float*)d_in[0];
    const float* t_eval = (const float*)d_in[1];
    const float* W0     = (const float*)d_in[2];
    const float* b0     = (const float*)d_in[3];
    const float* W1     = (const float*)d_in[4];
    const float* b1     = (const float*)d_in[5];
    const float* W2     = (const float*)d_in[6];
    const float* b2     = (const float*)d_in[7];
    const float* W3     = (const float*)d_in[8];
    const float* b3     = (const float*)d_in[9];
    float* out          = (float*)d_out;

    dim3 grid(N_B / 16);  // 4 waves/block x 4 trajectories/wave
    dim3 block(256);
    hipLaunchKernelGGL(ode_tsit5_kernel, grid, block, 0, stream,
                       x0s, t_eval, W0, b0, W1, b1, W2, b2, W3, b3, out);
}